// Round 12
// baseline (220.027 us; speedup 1.0000x reference)
//
#include <hip/hip_runtime.h>
#include <hip/hip_fp16.h>
#include <string.h>

#define NN 30000
#define NE 480000
#define CAP 96
#define KSC (0.0625f * 1.44269504f)   // SCALE * log2(e): exp(q*k/16) = exp2(q*kk)

typedef __attribute__((ext_vector_type(8))) _Float16 f16x8;
typedef __attribute__((ext_vector_type(4))) float f32x4;
typedef __attribute__((ext_vector_type(4))) int i32x4;
typedef __attribute__((ext_vector_type(2))) unsigned int u32x2;

__device__ __forceinline__ unsigned short f2h(float f) {
    _Float16 h = (_Float16)f;
    unsigned short u;
    memcpy(&u, &h, 2);
    return u;
}

__device__ __forceinline__ void gload16(const void* g, void* l) {
    __builtin_amdgcn_global_load_lds(
        (const __attribute__((address_space(1))) unsigned int*)g,
        (__attribute__((address_space(3))) unsigned int*)l, 16, 0, 0);
}

// ---------------- fused prologue: LN | Wqkv transpose | init ----------------
__global__ __launch_bounds__(256) void prologue_kernel(const float* __restrict__ s,
                                                       const float* __restrict__ gamma,
                                                       const float* __restrict__ beta,
                                                       unsigned short* __restrict__ xh,
                                                       const float* __restrict__ W,
                                                       unsigned short* __restrict__ WT,
                                                       int* __restrict__ cur,
                                                       unsigned int* __restrict__ colu,
                                                       unsigned int* __restrict__ qsu,
                                                       unsigned int* __restrict__ vsu) {
    const int bid = blockIdx.x;
    if (bid < NN) {
        // ---- LayerNorm ----
        const int n = bid;
        const int c = threadIdx.x;
        float v = s[n * 256 + c];
        float sum = v, sq = v * v;
        for (int o = 32; o; o >>= 1) {
            sum += __shfl_down(sum, o, 64);
            sq  += __shfl_down(sq,  o, 64);
        }
        __shared__ float ssum[4], ssq[4];
        const int wave = c >> 6, lane = c & 63;
        if (lane == 0) { ssum[wave] = sum; ssq[wave] = sq; }
        __syncthreads();
        float ts = ssum[0] + ssum[1] + ssum[2] + ssum[3];
        float tq = ssq[0]  + ssq[1]  + ssq[2]  + ssq[3];
        float mu  = ts * (1.0f / 256.0f);
        float var = tq * (1.0f / 256.0f) - mu * mu;
        float x = (v - mu) * rsqrtf(var + 1e-5f) * gamma[c] + beta[c];
        xh[n * 256 + c] = f2h(x);
    } else if (bid < NN + 768) {
        // ---- W transpose -> fp16 ----
        const int idx = (bid - NN) * 256 + threadIdx.x;   // 0..196607
        const int n = idx >> 8;
        const int k = idx & 255;
        WT[idx] = f2h(W[k * 768 + n]);
    } else {
        // ---- init: sentinel col fill, cursor zero, sentinel q/v rows ----
        const int i = (bid - NN - 768) * 256 + threadIdx.x;
        const unsigned int sent2 = (unsigned int)NN | ((unsigned int)NN << 16);
        if (i < NN * CAP / 2) colu[i] = sent2;
        if (i < NN) cur[i] = 0;
        if (i < 8 * 16) {
            const int x = i >> 4, j = i & 15;
            qsu[((size_t)x * (NN + 1) + NN) * 16 + j] = 0u;
            vsu[((size_t)x * (NN + 1) + NN) * 16 + j] = 0u;
        }
    }
}

__global__ __launch_bounds__(256) void scatter_kernel(const int* __restrict__ src,
                                                      const int* __restrict__ dst,
                                                      int* __restrict__ cursor,
                                                      unsigned short* __restrict__ col) {
    const int e = blockIdx.x * 256 + threadIdx.x;
    if (e < NE) {
        const int d = dst[e];
        const int slot = atomicAdd(&cursor[d], 1);
        if (slot < CAP) col[d * CAP + slot] = (unsigned short)src[e];
    }
}

// ---------------- GEMM: m97-style, XCD-banded, sliced epilogue ----------------
#define BM 128
#define BN 128
#define BK 32
#define CSTRIDE 136
#define MTILES 235   // ceil(30000/128)

__global__ __launch_bounds__(256) void gemm_kernel(const unsigned short* __restrict__ A,
                                                   const unsigned short* __restrict__ B,
                                                   unsigned short* __restrict__ qb,   // [8][NN+1][32]
                                                   unsigned short* __restrict__ kb,   // [8][NN][32]
                                                   unsigned short* __restrict__ vb) { // [8][NN+1][32]
    const int f   = blockIdx.x;          // 0..1439
    const int xcd = f & 7;
    const int i   = f >> 3;              // 0..179
    const int bmi = xcd * 30 + i / 6;
    if (bmi >= MTILES) return;
    const int bm = bmi * BM;
    const int by = i % 6;
    const int bn = by * BN;

    __shared__ unsigned short smem[BM * CSTRIDE];
    unsigned short* As = smem;
    unsigned short* Bs = smem + 4096;

    const int tid  = threadIdx.x;
    const int lane = tid & 63;
    const int wave = tid >> 6;
    const int wm = (wave & 1) * 64;
    const int wn = (wave >> 1) * 64;
    const int l16  = lane & 15;
    const int quad = lane >> 4;

    const int srow = wave * 16 + (lane >> 2);
    const int ko   = (lane & 3) * 8;

    int gmA0 = bm + srow;       if (gmA0 >= NN) gmA0 = NN - 1;
    int gmA1 = bm + srow + 64;  if (gmA1 >= NN) gmA1 = NN - 1;
    const int gnB0 = bn + srow;
    const int gnB1 = bn + srow + 64;

    f32x4 acc[4][4] = {};

    for (int kt = 0; kt < 256; kt += BK) {
        gload16(A + (size_t)gmA0 * 256 + kt + ko, &As[(wave * 16) * 32]);
        gload16(A + (size_t)gmA1 * 256 + kt + ko, &As[(64 + wave * 16) * 32]);
        gload16(B + (size_t)gnB0 * 256 + kt + ko, &Bs[(wave * 16) * 32]);
        gload16(B + (size_t)gnB1 * 256 + kt + ko, &Bs[(64 + wave * 16) * 32]);
        __syncthreads();

        f16x8 af[4], bfr[4];
        #pragma unroll
        for (int ii = 0; ii < 4; ii++)
            af[ii]  = *(const f16x8*)(&As[(wm + ii * 16 + l16) * 32 + quad * 8]);
        #pragma unroll
        for (int j = 0; j < 4; j++)
            bfr[j] = *(const f16x8*)(&Bs[(wn + j * 16 + l16) * 32 + quad * 8]);
        #pragma unroll
        for (int ii = 0; ii < 4; ii++)
            #pragma unroll
            for (int j = 0; j < 4; j++)
                acc[ii][j] = __builtin_amdgcn_mfma_f32_16x16x32_f16(af[ii], bfr[j], acc[ii][j], 0, 0, 0);
        __syncthreads();
    }

    #pragma unroll
    for (int ii = 0; ii < 4; ii++)
        #pragma unroll
        for (int j = 0; j < 4; j++)
            #pragma unroll
            for (int r = 0; r < 4; r++)
                smem[(wm + ii * 16 + quad * 4 + r) * CSTRIDE + wn + j * 16 + l16] =
                    f2h(acc[ii][j][r]);
    __syncthreads();

    const int sector  = by >> 1;                 // 0=q,1=k,2=v
    const int colhalf = (by & 1) * 128;
    const int row  = tid >> 1;
    const int cseg = (tid & 1) * 64;
    const int grow = bm + row;
    if (grow < NN) {
        #pragma unroll
        for (int k = 0; k < 8; k++) {
            i32x4 val = *(const i32x4*)(&smem[row * CSTRIDE + cseg + k * 8]);
            const int c = colhalf + cseg + k * 8;    // 8-aligned, 0..255
            const int x = c >> 5;                    // slice
            if (sector == 1)
                *(i32x4*)(kb + ((size_t)x * NN + grow) * 32 + (c & 31)) = val;
            else if (sector == 0)
                *(i32x4*)(qb + ((size_t)x * (NN + 1) + grow) * 32 + (c & 31)) = val;
            else
                *(i32x4*)(vb + ((size_t)x * (NN + 1) + grow) * 32 + (c & 31)) = val;
        }
    }
}

// ---------------- edge: 32-node sort, 8 nodes/wave, 4 ch/lane, int offsets ----------------
#define SSTRIDE 100   // scol row stride in ints (96 would be 8-way bank conflict)

__global__ __launch_bounds__(256) void edge_kernel(const unsigned short* __restrict__ qs,  // [8][NN+1][32]
                                                   const unsigned short* __restrict__ vs,  // [8][NN+1][32]
                                                   const unsigned short* __restrict__ ks,  // [8][NN][32]
                                                   const int* __restrict__ cursor,
                                                   const unsigned short* __restrict__ col, // [NN][CAP] sentinel-padded
                                                   float* __restrict__ out,
                                                   int ybase) {
    const int x   = blockIdx.x;                 // slice 0..7 -> XCD (round-robin)
    const int nb  = (ybase + blockIdx.y) * 32;  // block's 32 nodes
    const int tid = threadIdx.x;
    const int w   = tid >> 6;
    const int lane = tid & 63;

    __shared__ int scol[32 * SSTRIDE];          // 12800 B, byte offsets (src*64)
    __shared__ int sdegR[32], sdegS[32], snode[32];

    if (tid < 32) {
        const int n0 = nb + tid;
        int d = (n0 < NN) ? cursor[n0] : 0;
        sdegR[tid] = (d > CAP) ? CAP : d;
    }
    __syncthreads();
    if (tid < 32) {
        const int d = sdegR[tid];
        int r = 0;
        #pragma unroll
        for (int j = 0; j < 32; ++j) {
            const int dj = sdegR[j];
            r += (dj < d) || (dj == d && j < tid);
        }
        sdegS[r] = d;
        snode[r] = nb + tid;
    }
    __syncthreads();
    {   // stage col rows (sorted order), unpack ushort pairs -> pre-shifted byte offsets
        const unsigned int* colu = (const unsigned int*)col;
        #pragma unroll
        for (int j = 0; j < 6; j++) {
            const int t2 = tid + j * 256;            // 0..1535
            const int nd = t2 / 48;                  // local rank 0..31
            const int ps = t2 - nd * 48;             // uint pos 0..47
            const int sn = snode[nd];
            const int row = (sn < NN) ? sn : 0;
            const unsigned int u = colu[row * 48 + ps];
            scol[nd * SSTRIDE + 2 * ps]     = (int)(u & 0xffffu) << 6;
            scol[nd * SSTRIDE + 2 * ps + 1] = (int)(u >> 16) << 6;
        }
    }
    __syncthreads();

    const int g  = lane >> 3;                   // node-in-wave 0..7
    const int cq = lane & 7;                    // channel quad (4 ch)
    const int li = w * 8 + g;
    const int m  = snode[li];
    const int msafe = (m < NN) ? m : NN - 1;

    const int mydeg = sdegS[li];
    const int dmax4 = (sdegS[w * 8 + 7] + 3) & ~3;   // octet max (sorted), round to 4

    union U { unsigned int u; __half2 h; };
    u32x2 kraw = *(const u32x2*)(ks + ((size_t)x * NN + msafe) * 32 + 4 * cq);
    U t0, t1; t0.u = kraw.x; t1.u = kraw.y;
    const __half2 ksc2 = __float2half2_rn(KSC);
    const __half2 kkA = __hmul2(t0.h, ksc2);
    const __half2 kkB = __hmul2(t1.h, ksc2);

    const char* qp = (const char*)qs + (size_t)x * (NN + 1) * 64 + cq * 8;
    const char* vp = (const char*)vs + (size_t)x * (NN + 1) * 64 + cq * 8;
    const int* myscol = &scol[li * SSTRIDE];

    __half2 zA = __float2half2_rn(0.0f), zB = __float2half2_rn(0.0f);
    __half2 aA = __float2half2_rn(0.0f), aB = __float2half2_rn(0.0f);

    for (int i = 0; i < dmax4; i += 4) {
        const i32x4 off4 = *(const i32x4*)(&myscol[i]);   // 4 byte-offsets, one ds_read_b128
        #pragma unroll
        for (int j = 0; j < 4; j++) {
            const int off = off4[j];                      // sentinel -> NN*64 (zero row)
            const u32x2 qd = *(const u32x2*)(qp + off);
            const u32x2 vd = *(const u32x2*)(vp + off);
            U qa, qb2, va, vb2;
            qa.u = qd.x; qb2.u = qd.y; va.u = vd.x; vb2.u = vd.y;
            const __half2 w0 = h2exp2(__hmul2(qa.h, kkA));   // sentinel: exp2(0)=1
            const __half2 w1 = h2exp2(__hmul2(qb2.h, kkB));
            zA = __hadd2(zA, w0);
            aA = __hfma2(w0, va.h, aA);
            zB = __hadd2(zB, w1);
            aB = __hfma2(w1, vb2.h, aB);
        }
    }

    // sentinel pads contributed exactly 1.0 to each z lane, 0.0 to a — exact correction:
    const float npad = (float)(dmax4 - mydeg);
    f32x4 o;
    const float z0 = __low2float(zA)  - npad;
    const float z1 = __high2float(zA) - npad;
    const float z2 = __low2float(zB)  - npad;
    const float z3 = __high2float(zB) - npad;
    o[0] = (mydeg > 0) ? __low2float(aA)  / z0 : 0.0f;
    o[1] = (mydeg > 0) ? __high2float(aA) / z1 : 0.0f;
    o[2] = (mydeg > 0) ? __low2float(aB)  / z2 : 0.0f;
    o[3] = (mydeg > 0) ? __high2float(aB) / z3 : 0.0f;
    if (m < NN)
        *(f32x4*)(out + (size_t)m * 256 + x * 32 + 4 * cq) = o;
}

extern "C" void kernel_launch(void* const* d_in, const int* in_sizes, int n_in,
                              void* d_out, int out_size, void* d_ws, size_t ws_size,
                              hipStream_t stream) {
    const float* s     = (const float*)d_in[0];
    const float* Wqkv  = (const float*)d_in[1];
    const float* gamma = (const float*)d_in[2];
    const float* beta  = (const float*)d_in[3];
    const int*   src   = (const int*)d_in[4];
    const int*   dst   = (const int*)d_in[5];
    float* out = (float*)d_out;

    char* ws = (char*)d_ws;
    unsigned short* xh   = (unsigned short*)(ws);                   // 15,360,000
    unsigned short* WT   = (unsigned short*)(ws + 15360000);        //    393,216
    unsigned short* qs   = (unsigned short*)(ws + 15753216);        // 15,360,512  [8][NN+1][32]
    unsigned short* vs   = (unsigned short*)(ws + 31113728);        // 15,360,512
    unsigned short* ks   = (unsigned short*)(ws + 46474240);        // 15,360,000  [8][NN][32]
    int*            cur  = (int*)(ws + 61834240);                   //    120,000
    unsigned short* col  = (unsigned short*)(ws + 61954240);        //  5,760,000  (~67.7 MB)

    const int init_blocks = (NN * CAP / 2 + 255) / 256;             // 5625
    prologue_kernel<<<NN + 768 + init_blocks, 256, 0, stream>>>(
        s, gamma, beta, xh, Wqkv, WT, cur,
        (unsigned int*)col, (unsigned int*)qs, (unsigned int*)vs);
    scatter_kernel<<<(NE + 255) / 256, 256, 0, stream>>>(src, dst, cur, col);
    gemm_kernel<<<1440, 256, 0, stream>>>(xh, WT, qs, ks, vs);
    // 938 y-blocks of 32 nodes, split in two dispatches (top-5 visibility for gemm)
    edge_kernel<<<dim3(8, 469), 256, 0, stream>>>(qs, vs, ks, cur, col, out, 0);
    edge_kernel<<<dim3(8, 469), 256, 0, stream>>>(qs, vs, ks, cur, col, out, 469);
}

// Round 13
// 209.455 us; speedup vs baseline: 1.0505x; 1.0505x over previous
//
#include <hip/hip_runtime.h>
#include <hip/hip_fp16.h>
#include <string.h>

#define NN 30000
#define NE 480000
#define CAP 96
#define KSC (0.0625f * 1.44269504f)   // SCALE * log2(e): exp(q*k/16) = exp2(q*kk)

typedef __attribute__((ext_vector_type(8))) _Float16 f16x8;
typedef __attribute__((ext_vector_type(4))) float f32x4;
typedef __attribute__((ext_vector_type(4))) int i32x4;
typedef __attribute__((ext_vector_type(2))) unsigned int u32x2;

__device__ __forceinline__ unsigned short f2h(float f) {
    _Float16 h = (_Float16)f;
    unsigned short u;
    memcpy(&u, &h, 2);
    return u;
}

__device__ __forceinline__ void gload16(const void* g, void* l) {
    __builtin_amdgcn_global_load_lds(
        (const __attribute__((address_space(1))) unsigned int*)g,
        (__attribute__((address_space(3))) unsigned int*)l, 16, 0, 0);
}

// ---------------- fused prologue: LN | Wqkv transpose | init ----------------
__global__ __launch_bounds__(256) void prologue_kernel(const float* __restrict__ s,
                                                       const float* __restrict__ gamma,
                                                       const float* __restrict__ beta,
                                                       unsigned short* __restrict__ xh,
                                                       const float* __restrict__ W,
                                                       unsigned short* __restrict__ WT,
                                                       int* __restrict__ cur,
                                                       unsigned int* __restrict__ colu,
                                                       unsigned int* __restrict__ qvu) {
    const int bid = blockIdx.x;
    if (bid < NN) {
        // ---- LayerNorm ----
        const int n = bid;
        const int c = threadIdx.x;
        float v = s[n * 256 + c];
        float sum = v, sq = v * v;
        for (int o = 32; o; o >>= 1) {
            sum += __shfl_down(sum, o, 64);
            sq  += __shfl_down(sq,  o, 64);
        }
        __shared__ float ssum[4], ssq[4];
        const int wave = c >> 6, lane = c & 63;
        if (lane == 0) { ssum[wave] = sum; ssq[wave] = sq; }
        __syncthreads();
        float ts = ssum[0] + ssum[1] + ssum[2] + ssum[3];
        float tq = ssq[0]  + ssq[1]  + ssq[2]  + ssq[3];
        float mu  = ts * (1.0f / 256.0f);
        float var = tq * (1.0f / 256.0f) - mu * mu;
        float x = (v - mu) * rsqrtf(var + 1e-5f) * gamma[c] + beta[c];
        xh[n * 256 + c] = f2h(x);
    } else if (bid < NN + 768) {
        // ---- W transpose -> fp16 ----
        const int idx = (bid - NN) * 256 + threadIdx.x;   // 0..196607
        const int n = idx >> 8;
        const int k = idx & 255;
        WT[idx] = f2h(W[k * 768 + n]);
    } else {
        // ---- init: sentinel col fill, cursor zero, sentinel qv rows ----
        const int i = (bid - NN - 768) * 256 + threadIdx.x;
        const unsigned int sent2 = (unsigned int)NN | ((unsigned int)NN << 16);
        if (i < NN * CAP / 2) colu[i] = sent2;
        if (i < NN) cur[i] = 0;
        if (i < 8 * 32) {   // 8 slices x 32 uints = 128B sentinel row of qv
            const int x = i >> 5, j = i & 31;
            qvu[((size_t)x * (NN + 1) + NN) * 32 + j] = 0u;
        }
    }
}

__global__ __launch_bounds__(256) void scatter_kernel(const int* __restrict__ src,
                                                      const int* __restrict__ dst,
                                                      int* __restrict__ cursor,
                                                      unsigned short* __restrict__ col) {
    const int e = blockIdx.x * 256 + threadIdx.x;
    if (e < NE) {
        const int d = dst[e];
        const int slot = atomicAdd(&cursor[d], 1);
        if (slot < CAP) col[d * CAP + slot] = (unsigned short)src[e];
    }
}

// ---------------- GEMM: m97-style, XCD-banded, qv-interleaved epilogue ----------------
#define BM 128
#define BN 128
#define BK 32
#define CSTRIDE 136
#define MTILES 235   // ceil(30000/128)

__global__ __launch_bounds__(256) void gemm_kernel(const unsigned short* __restrict__ A,
                                                   const unsigned short* __restrict__ B,
                                                   unsigned short* __restrict__ qv,   // [8][NN+1][64]: 8x{4q,4v}
                                                   unsigned short* __restrict__ kb) { // [8][NN][32]
    const int f   = blockIdx.x;          // 0..1439
    const int xcd = f & 7;
    const int i   = f >> 3;              // 0..179
    const int bmi = xcd * 30 + i / 6;
    if (bmi >= MTILES) return;
    const int bm = bmi * BM;
    const int by = i % 6;
    const int bn = by * BN;

    __shared__ unsigned short smem[BM * CSTRIDE];
    unsigned short* As = smem;
    unsigned short* Bs = smem + 4096;

    const int tid  = threadIdx.x;
    const int lane = tid & 63;
    const int wave = tid >> 6;
    const int wm = (wave & 1) * 64;
    const int wn = (wave >> 1) * 64;
    const int l16  = lane & 15;
    const int quad = lane >> 4;

    const int srow = wave * 16 + (lane >> 2);
    const int ko   = (lane & 3) * 8;

    int gmA0 = bm + srow;       if (gmA0 >= NN) gmA0 = NN - 1;
    int gmA1 = bm + srow + 64;  if (gmA1 >= NN) gmA1 = NN - 1;
    const int gnB0 = bn + srow;
    const int gnB1 = bn + srow + 64;

    f32x4 acc[4][4] = {};

    for (int kt = 0; kt < 256; kt += BK) {
        gload16(A + (size_t)gmA0 * 256 + kt + ko, &As[(wave * 16) * 32]);
        gload16(A + (size_t)gmA1 * 256 + kt + ko, &As[(64 + wave * 16) * 32]);
        gload16(B + (size_t)gnB0 * 256 + kt + ko, &Bs[(wave * 16) * 32]);
        gload16(B + (size_t)gnB1 * 256 + kt + ko, &Bs[(64 + wave * 16) * 32]);
        __syncthreads();

        f16x8 af[4], bfr[4];
        #pragma unroll
        for (int ii = 0; ii < 4; ii++)
            af[ii]  = *(const f16x8*)(&As[(wm + ii * 16 + l16) * 32 + quad * 8]);
        #pragma unroll
        for (int j = 0; j < 4; j++)
            bfr[j] = *(const f16x8*)(&Bs[(wn + j * 16 + l16) * 32 + quad * 8]);
        #pragma unroll
        for (int ii = 0; ii < 4; ii++)
            #pragma unroll
            for (int j = 0; j < 4; j++)
                acc[ii][j] = __builtin_amdgcn_mfma_f32_16x16x32_f16(af[ii], bfr[j], acc[ii][j], 0, 0, 0);
        __syncthreads();
    }

    #pragma unroll
    for (int ii = 0; ii < 4; ii++)
        #pragma unroll
        for (int j = 0; j < 4; j++)
            #pragma unroll
            for (int r = 0; r < 4; r++)
                smem[(wm + ii * 16 + quad * 4 + r) * CSTRIDE + wn + j * 16 + l16] =
                    f2h(acc[ii][j][r]);
    __syncthreads();

    const int sector  = by >> 1;                 // 0=q,1=k,2=v
    const int colhalf = (by & 1) * 128;
    const int row  = tid >> 1;
    const int cseg = (tid & 1) * 64;
    const int grow = bm + row;
    if (grow < NN) {
        #pragma unroll
        for (int k = 0; k < 8; k++) {
            i32x4 val = *(const i32x4*)(&smem[row * CSTRIDE + cseg + k * 8]);
            const int c = colhalf + cseg + k * 8;    // 8-aligned, 0..255
            const int x = c >> 5;                    // slice
            if (sector == 1) {
                *(i32x4*)(kb + ((size_t)x * NN + grow) * 32 + (c & 31)) = val;
            } else {
                // qv group layout: group j ushorts 8j..8j+3 = q-quad, 8j+4..8j+7 = v-quad
                unsigned short* base = qv + ((size_t)x * (NN + 1) + grow) * 64
                                       + ((c & 31) >> 2) * 8 + (sector == 2 ? 4 : 0);
                u32x2 lo, hi;
                lo.x = (unsigned int)val[0]; lo.y = (unsigned int)val[1];
                hi.x = (unsigned int)val[2]; hi.y = (unsigned int)val[3];
                *(u32x2*)(base)     = lo;   // channels quad (c&31)/4
                *(u32x2*)(base + 8) = hi;   // channels quad (c&31)/4 + 1
            }
        }
    }
}

// ---------------- edge: 32-node sort, 8 nodes/wave, 4 ch/lane, ONE qv gather ----------------
#define SSTRIDE 100   // scol row stride in ints (96 would be 8-way bank conflict)

__global__ __launch_bounds__(256) void edge_kernel(const unsigned short* __restrict__ qv,  // [8][NN+1][64]
                                                   const unsigned short* __restrict__ ks,  // [8][NN][32]
                                                   const int* __restrict__ cursor,
                                                   const unsigned short* __restrict__ col, // [NN][CAP] sentinel-padded
                                                   float* __restrict__ out) {
    const int x   = blockIdx.x;                 // slice 0..7 -> XCD (round-robin)
    const int nb  = blockIdx.y * 32;            // block's 32 nodes
    const int tid = threadIdx.x;
    const int w   = tid >> 6;
    const int lane = tid & 63;

    __shared__ int scol[32 * SSTRIDE];          // 12800 B, byte offsets (src*128)
    __shared__ int sdegR[32], sdegS[32], snode[32];

    if (tid < 32) {
        const int n0 = nb + tid;
        int d = (n0 < NN) ? cursor[n0] : 0;
        sdegR[tid] = (d > CAP) ? CAP : d;
    }
    __syncthreads();
    if (tid < 32) {
        const int d = sdegR[tid];
        int r = 0;
        #pragma unroll
        for (int j = 0; j < 32; ++j) {
            const int dj = sdegR[j];
            r += (dj < d) || (dj == d && j < tid);
        }
        sdegS[r] = d;
        snode[r] = nb + tid;
    }
    __syncthreads();
    {   // stage col rows (sorted order), unpack ushorts -> pre-shifted byte offsets (<<7)
        const unsigned int* colu = (const unsigned int*)col;
        #pragma unroll
        for (int j = 0; j < 6; j++) {
            const int t2 = tid + j * 256;            // 0..1535
            const int nd = t2 / 48;                  // local rank 0..31
            const int ps = t2 - nd * 48;             // uint pos 0..47
            const int sn = snode[nd];
            const int row = (sn < NN) ? sn : 0;
            const unsigned int u = colu[row * 48 + ps];
            scol[nd * SSTRIDE + 2 * ps]     = (int)(u & 0xffffu) << 7;
            scol[nd * SSTRIDE + 2 * ps + 1] = (int)(u >> 16) << 7;
        }
    }
    __syncthreads();

    const int g  = lane >> 3;                   // node-in-wave 0..7
    const int cq = lane & 7;                    // channel quad (4 ch)
    const int li = w * 8 + g;
    const int m  = snode[li];
    const int msafe = (m < NN) ? m : NN - 1;

    const int mydeg = sdegS[li];
    const int dmax4 = (sdegS[w * 8 + 7] + 3) & ~3;   // octet max (sorted), round to 4

    union U { unsigned int u; __half2 h; };
    u32x2 kraw = *(const u32x2*)(ks + ((size_t)x * NN + msafe) * 32 + 4 * cq);
    U t0, t1; t0.u = kraw.x; t1.u = kraw.y;
    const __half2 ksc2 = __float2half2_rn(KSC);
    const __half2 kkA = __hmul2(t0.h, ksc2);
    const __half2 kkB = __hmul2(t1.h, ksc2);

    const char* qvp = (const char*)qv + (size_t)x * (NN + 1) * 128 + cq * 16;
    const int* myscol = &scol[li * SSTRIDE];

    __half2 zA = __float2half2_rn(0.0f), zB = __float2half2_rn(0.0f);
    __half2 aA = __float2half2_rn(0.0f), aB = __float2half2_rn(0.0f);

    for (int i = 0; i < dmax4; i += 4) {
        const i32x4 off4 = *(const i32x4*)(&myscol[i]);   // 4 byte-offsets, one ds_read_b128
        #pragma unroll
        for (int j = 0; j < 4; j++) {
            const i32x4 d4 = *(const i32x4*)(qvp + off4[j]);   // {q01,q23,v01,v23}
            U q01, q23, v01, v23;
            q01.u = (unsigned int)d4[0];
            q23.u = (unsigned int)d4[1];
            v01.u = (unsigned int)d4[2];
            v23.u = (unsigned int)d4[3];
            const __half2 w0 = h2exp2(__hmul2(q01.h, kkA));   // sentinel: exp2(0)=1
            const __half2 w1 = h2exp2(__hmul2(q23.h, kkB));
            zA = __hadd2(zA, w0);
            aA = __hfma2(w0, v01.h, aA);
            zB = __hadd2(zB, w1);
            aB = __hfma2(w1, v23.h, aB);
        }
    }

    // sentinel pads contributed exactly 1.0 to each z lane, 0.0 to a — exact correction:
    const float npad = (float)(dmax4 - mydeg);
    f32x4 o;
    const float z0 = __low2float(zA)  - npad;
    const float z1 = __high2float(zA) - npad;
    const float z2 = __low2float(zB)  - npad;
    const float z3 = __high2float(zB) - npad;
    o[0] = (mydeg > 0) ? __low2float(aA)  / z0 : 0.0f;
    o[1] = (mydeg > 0) ? __high2float(aA) / z1 : 0.0f;
    o[2] = (mydeg > 0) ? __low2float(aB)  / z2 : 0.0f;
    o[3] = (mydeg > 0) ? __high2float(aB) / z3 : 0.0f;
    if (m < NN)
        *(f32x4*)(out + (size_t)m * 256 + x * 32 + 4 * cq) = o;
}

extern "C" void kernel_launch(void* const* d_in, const int* in_sizes, int n_in,
                              void* d_out, int out_size, void* d_ws, size_t ws_size,
                              hipStream_t stream) {
    const float* s     = (const float*)d_in[0];
    const float* Wqkv  = (const float*)d_in[1];
    const float* gamma = (const float*)d_in[2];
    const float* beta  = (const float*)d_in[3];
    const int*   src   = (const int*)d_in[4];
    const int*   dst   = (const int*)d_in[5];
    float* out = (float*)d_out;

    char* ws = (char*)d_ws;
    unsigned short* xh   = (unsigned short*)(ws);                   // 15,360,000
    unsigned short* WT   = (unsigned short*)(ws + 15360000);        //    393,216
    unsigned short* qv   = (unsigned short*)(ws + 15753216);        // 30,721,024  [8][NN+1][64]
    unsigned short* ks   = (unsigned short*)(ws + 46474240);        // 15,360,000  [8][NN][32]
    int*            cur  = (int*)(ws + 61834240);                   //    120,000
    unsigned short* col  = (unsigned short*)(ws + 61954240);        //  5,760,000  (~67.7 MB)

    const int init_blocks = (NN * CAP / 2 + 255) / 256;             // 5625
    prologue_kernel<<<NN + 768 + init_blocks, 256, 0, stream>>>(
        s, gamma, beta, xh, Wqkv, WT, cur,
        (unsigned int*)col, (unsigned int*)qv);
    scatter_kernel<<<(NE + 255) / 256, 256, 0, stream>>>(src, dst, cur, col);
    gemm_kernel<<<1440, 256, 0, stream>>>(xh, WT, qv, ks);
    edge_kernel<<<dim3(8, (NN + 31) / 32), 256, 0, stream>>>(qv, ks, cur, col, out);
}

// Round 15
// 207.848 us; speedup vs baseline: 1.0586x; 1.0077x over previous
//
#include <hip/hip_runtime.h>
#include <hip/hip_fp16.h>
#include <string.h>

#define NN 30000
#define NE 480000
#define CAP 96
#define KSC (0.0625f * 1.44269504f)   // SCALE * log2(e): exp(q*k/16) = exp2(q*kk)

typedef __attribute__((ext_vector_type(8))) _Float16 f16x8;
typedef __attribute__((ext_vector_type(4))) float f32x4;
typedef __attribute__((ext_vector_type(4))) int i32x4;
typedef __attribute__((ext_vector_type(2))) unsigned int u32x2;

__device__ __forceinline__ unsigned short f2h(float f) {
    _Float16 h = (_Float16)f;
    unsigned short u;
    memcpy(&u, &h, 2);
    return u;
}

__device__ __forceinline__ void gload16(const void* g, void* l) {
    __builtin_amdgcn_global_load_lds(
        (const __attribute__((address_space(1))) unsigned int*)g,
        (__attribute__((address_space(3))) unsigned int*)l, 16, 0, 0);
}

// ---------------- fused prologue: LN | Wqkv transpose | init ----------------
__global__ __launch_bounds__(256) void prologue_kernel(const float* __restrict__ s,
                                                       const float* __restrict__ gamma,
                                                       const float* __restrict__ beta,
                                                       unsigned short* __restrict__ xh,
                                                       const float* __restrict__ W,
                                                       unsigned short* __restrict__ WT,
                                                       int* __restrict__ cur,
                                                       unsigned int* __restrict__ colu,
                                                       unsigned int* __restrict__ qvu) {
    const int bid = blockIdx.x;
    if (bid < NN) {
        // ---- LayerNorm ----
        const int n = bid;
        const int c = threadIdx.x;
        float v = s[n * 256 + c];
        float sum = v, sq = v * v;
        for (int o = 32; o; o >>= 1) {
            sum += __shfl_down(sum, o, 64);
            sq  += __shfl_down(sq,  o, 64);
        }
        __shared__ float ssum[4], ssq[4];
        const int wave = c >> 6, lane = c & 63;
        if (lane == 0) { ssum[wave] = sum; ssq[wave] = sq; }
        __syncthreads();
        float ts = ssum[0] + ssum[1] + ssum[2] + ssum[3];
        float tq = ssq[0]  + ssq[1]  + ssq[2]  + ssq[3];
        float mu  = ts * (1.0f / 256.0f);
        float var = tq * (1.0f / 256.0f) - mu * mu;
        float x = (v - mu) * rsqrtf(var + 1e-5f) * gamma[c] + beta[c];
        xh[n * 256 + c] = f2h(x);
    } else if (bid < NN + 768) {
        // ---- W transpose -> fp16 ----
        const int idx = (bid - NN) * 256 + threadIdx.x;   // 0..196607
        const int n = idx >> 8;
        const int k = idx & 255;
        WT[idx] = f2h(W[k * 768 + n]);
    } else {
        // ---- init: sentinel col fill, cursor zero, sentinel qv rows ----
        const int i = (bid - NN - 768) * 256 + threadIdx.x;
        const unsigned int sent2 = (unsigned int)NN | ((unsigned int)NN << 16);
        if (i < NN * CAP / 2) colu[i] = sent2;
        if (i < NN) cur[i] = 0;
        if (i < 8 * 32) {   // 8 slices x 32 uints = 128B sentinel row of qv
            const int x = i >> 5, j = i & 31;
            qvu[((size_t)x * (NN + 1) + NN) * 32 + j] = 0u;
        }
    }
}

__global__ __launch_bounds__(256) void scatter_kernel(const int* __restrict__ src,
                                                      const int* __restrict__ dst,
                                                      int* __restrict__ cursor,
                                                      unsigned short* __restrict__ col) {
    const int e = blockIdx.x * 256 + threadIdx.x;
    if (e < NE) {
        const int d = dst[e];
        const int slot = atomicAdd(&cursor[d], 1);
        if (slot < CAP) col[d * CAP + slot] = (unsigned short)src[e];
    }
}

// ---------------- GEMM: m97-style, XCD-banded, BK=64, qv-interleaved epilogue ----------------
#define BM 128
#define BN 128
#define BK 64
#define CSTRIDE 136
#define MTILES 235   // ceil(30000/128)

__global__ __launch_bounds__(256) void gemm_kernel(const unsigned short* __restrict__ A,
                                                   const unsigned short* __restrict__ B,
                                                   unsigned short* __restrict__ qv,   // [8][NN+1][64]: 8x{4q,4v}
                                                   unsigned short* __restrict__ kb) { // [8][NN][32]
    const int f   = blockIdx.x;          // 0..1439
    const int xcd = f & 7;
    const int i   = f >> 3;              // 0..179
    const int bmi = xcd * 30 + i / 6;
    if (bmi >= MTILES) return;
    const int bm = bmi * BM;
    const int by = i % 6;
    const int bn = by * BN;

    __shared__ unsigned short smem[BM * CSTRIDE];   // 17408 ushorts; As(8192)+Bs(8192) fit
    unsigned short* As = smem;          // [128][64]
    unsigned short* Bs = smem + 8192;   // [128][64]

    const int tid  = threadIdx.x;
    const int lane = tid & 63;
    const int wave = tid >> 6;
    const int wm = (wave & 1) * 64;
    const int wn = (wave >> 1) * 64;
    const int l16  = lane & 15;
    const int quad = lane >> 4;

    // staging: wave w, pass j covers rows w*8 + 32*j .. +7; lane l -> row +(l>>3), chunk (l&7)*8
    const int srow0 = wave * 8 + (lane >> 3);
    const int ko    = (lane & 7) * 8;

    f32x4 acc[4][4] = {};

    for (int kt = 0; kt < 256; kt += BK) {
        #pragma unroll
        for (int j = 0; j < 4; j++) {
            const int r = srow0 + 32 * j;
            int gmA = bm + r; if (gmA >= NN) gmA = NN - 1;
            gload16(A + (size_t)gmA * 256 + kt + ko, &As[(wave * 8 + 32 * j) * 64]);
            gload16(B + (size_t)(bn + r) * 256 + kt + ko, &Bs[(wave * 8 + 32 * j) * 64]);
        }
        __syncthreads();

        #pragma unroll
        for (int ks = 0; ks < 2; ks++) {
            f16x8 af[4], bfr[4];
            #pragma unroll
            for (int ii = 0; ii < 4; ii++)
                af[ii]  = *(const f16x8*)(&As[(wm + ii * 16 + l16) * 64 + ks * 32 + quad * 8]);
            #pragma unroll
            for (int jj = 0; jj < 4; jj++)
                bfr[jj] = *(const f16x8*)(&Bs[(wn + jj * 16 + l16) * 64 + ks * 32 + quad * 8]);
            #pragma unroll
            for (int ii = 0; ii < 4; ii++)
                #pragma unroll
                for (int jj = 0; jj < 4; jj++)
                    acc[ii][jj] = __builtin_amdgcn_mfma_f32_16x16x32_f16(af[ii], bfr[jj], acc[ii][jj], 0, 0, 0);
        }
        __syncthreads();
    }

    // ---- epilogue: transpose through LDS, write interleaved fp16 qv + k ----
    #pragma unroll
    for (int ii = 0; ii < 4; ii++)
        #pragma unroll
        for (int jj = 0; jj < 4; jj++)
            #pragma unroll
            for (int r = 0; r < 4; r++)
                smem[(wm + ii * 16 + quad * 4 + r) * CSTRIDE + wn + jj * 16 + l16] =
                    f2h(acc[ii][jj][r]);
    __syncthreads();

    const int sector  = by >> 1;                 // 0=q,1=k,2=v
    const int colhalf = (by & 1) * 128;
    const int row  = tid >> 1;
    const int cseg = (tid & 1) * 64;
    const int grow = bm + row;
    if (grow < NN) {
        #pragma unroll
        for (int k = 0; k < 8; k++) {
            i32x4 val = *(const i32x4*)(&smem[row * CSTRIDE + cseg + k * 8]);
            const int c = colhalf + cseg + k * 8;    // 8-aligned, 0..255
            const int x = c >> 5;                    // slice
            if (sector == 1) {
                *(i32x4*)(kb + ((size_t)x * NN + grow) * 32 + (c & 31)) = val;
            } else {
                // qv group layout: group j ushorts 8j..8j+3 = q-quad, 8j+4..8j+7 = v-quad
                unsigned short* base = qv + ((size_t)x * (NN + 1) + grow) * 64
                                       + ((c & 31) >> 2) * 8 + (sector == 2 ? 4 : 0);
                u32x2 lo, hi;
                lo.x = (unsigned int)val[0]; lo.y = (unsigned int)val[1];
                hi.x = (unsigned int)val[2]; hi.y = (unsigned int)val[3];
                *(u32x2*)(base)     = lo;   // channels quad (c&31)/4
                *(u32x2*)(base + 8) = hi;   // channels quad (c&31)/4 + 1
            }
        }
    }
}

// ---------------- edge: 32-node sort, 8 nodes/wave, 4 ch/lane, ONE qv gather ----------------
#define SSTRIDE 100   // scol row stride in ints (96 would be 8-way bank conflict)

__global__ __launch_bounds__(256) void edge_kernel(const unsigned short* __restrict__ qv,  // [8][NN+1][64]
                                                   const unsigned short* __restrict__ ks,  // [8][NN][32]
                                                   const int* __restrict__ cursor,
                                                   const unsigned short* __restrict__ col, // [NN][CAP] sentinel-padded
                                                   float* __restrict__ out) {
    const int x   = blockIdx.x;                 // slice 0..7 -> XCD (round-robin)
    const int nb  = blockIdx.y * 32;            // block's 32 nodes
    const int tid = threadIdx.x;
    const int w   = tid >> 6;
    const int lane = tid & 63;

    __shared__ int scol[32 * SSTRIDE];          // 12800 B, byte offsets (src*128)
    __shared__ int sdegR[32], sdegS[32], snode[32];

    if (tid < 32) {
        const int n0 = nb + tid;
        int d = (n0 < NN) ? cursor[n0] : 0;
        sdegR[tid] = (d > CAP) ? CAP : d;
    }
    __syncthreads();
    if (tid < 32) {
        const int d = sdegR[tid];
        int r = 0;
        #pragma unroll
        for (int j = 0; j < 32; ++j) {
            const int dj = sdegR[j];
            r += (dj < d) || (dj == d && j < tid);
        }
        sdegS[r] = d;
        snode[r] = nb + tid;
    }
    __syncthreads();
    {   // stage col rows (sorted order), unpack ushorts -> pre-shifted byte offsets (<<7)
        const unsigned int* colu = (const unsigned int*)col;
        #pragma unroll
        for (int j = 0; j < 6; j++) {
            const int t2 = tid + j * 256;            // 0..1535
            const int nd = t2 / 48;                  // local rank 0..31
            const int ps = t2 - nd * 48;             // uint pos 0..47
            const int sn = snode[nd];
            const int row = (sn < NN) ? sn : 0;
            const unsigned int u = colu[row * 48 + ps];
            scol[nd * SSTRIDE + 2 * ps]     = (int)(u & 0xffffu) << 7;
            scol[nd * SSTRIDE + 2 * ps + 1] = (int)(u >> 16) << 7;
        }
    }
    __syncthreads();

    const int g  = lane >> 3;                   // node-in-wave 0..7
    const int cq = lane & 7;                    // channel quad (4 ch)
    const int li = w * 8 + g;
    const int m  = snode[li];
    const int msafe = (m < NN) ? m : 0;

    const int mydeg = sdegS[li];
    const int dmax4 = (sdegS[w * 8 + 7] + 3) & ~3;   // octet max (sorted), round to 4

    union U { unsigned int u; __half2 h; };
    u32x2 kraw = *(const u32x2*)(ks + ((size_t)x * NN + msafe) * 32 + 4 * cq);
    U t0, t1; t0.u = kraw.x; t1.u = kraw.y;
    const __half2 ksc2 = __float2half2_rn(KSC);
    const __half2 kkA = __hmul2(t0.h, ksc2);
    const __half2 kkB = __hmul2(t1.h, ksc2);

    const char* qvp = (const char*)qv + (size_t)x * (NN + 1) * 128 + cq * 16;
    const int* myscol = &scol[li * SSTRIDE];

    __half2 zA = __float2half2_rn(0.0f), zB = __float2half2_rn(0.0f);
    __half2 aA = __float2half2_rn(0.0f), aB = __float2half2_rn(0.0f);

    for (int i = 0; i < dmax4; i += 4) {
        const i32x4 off4 = *(const i32x4*)(&myscol[i]);   // 4 byte-offsets, one ds_read_b128
        #pragma unroll
        for (int j = 0; j < 4; j++) {
            const i32x4 d4 = *(const i32x4*)(qvp + off4[j]);   // {q01,q23,v01,v23}
            U q01, q23, v01, v23;
            q01.u = (unsigned int)d4[0];
            q23.u = (unsigned int)d4[1];
            v01.u = (unsigned int)d4[2];
            v23.u = (unsigned int)d4[3];
            const __half2 w0 = h2exp2(__hmul2(q01.h, kkA));   // sentinel: exp2(0)=1
            const __half2 w1 = h2exp2(__hmul2(q23.h, kkB));
            zA = __hadd2(zA, w0);
            aA = __hfma2(w0, v01.h, aA);
            zB = __hadd2(zB, w1);
            aB = __hfma2(w1, v23.h, aB);
        }
    }

    // sentinel pads contributed exactly 1.0 to each z lane, 0.0 to a — exact correction:
    const float npad = (float)(dmax4 - mydeg);
    f32x4 o;
    const float z0 = __low2float(zA)  - npad;
    const float z1 = __high2float(zA) - npad;
    const float z2 = __low2float(zB)  - npad;
    const float z3 = __high2float(zB) - npad;
    o[0] = (mydeg > 0) ? __low2float(aA)  / z0 : 0.0f;
    o[1] = (mydeg > 0) ? __high2float(aA) / z1 : 0.0f;
    o[2] = (mydeg > 0) ? __low2float(aB)  / z2 : 0.0f;
    o[3] = (mydeg > 0) ? __high2float(aB) / z3 : 0.0f;
    if (m < NN)
        *(f32x4*)(out + (size_t)m * 256 + x * 32 + 4 * cq) = o;
}

extern "C" void kernel_launch(void* const* d_in, const int* in_sizes, int n_in,
                              void* d_out, int out_size, void* d_ws, size_t ws_size,
                              hipStream_t stream) {
    const float* s     = (const float*)d_in[0];
    const float* Wqkv  = (const float*)d_in[1];
    const float* gamma = (const float*)d_in[2];
    const float* beta  = (const float*)d_in[3];
    const int*   src   = (const int*)d_in[4];
    const int*   dst   = (const int*)d_in[5];
    float* out = (float*)d_out;

    char* ws = (char*)d_ws;
    unsigned short* xh   = (unsigned short*)(ws);                   // 15,360,000
    unsigned short* WT   = (unsigned short*)(ws + 15360000);        //    393,216
    unsigned short* qv   = (unsigned short*)(ws + 15753216);        // 30,721,024  [8][NN+1][64]
    unsigned short* ks   = (unsigned short*)(ws + 46474240);        // 15,360,000  [8][NN][32]
    int*            cur  = (int*)(ws + 61834240);                   //    120,000
    unsigned short* col  = (unsigned short*)(ws + 61954240);        //  5,760,000  (~67.7 MB)

    const int init_blocks = (NN * CAP / 2 + 255) / 256;             // 5625
    prologue_kernel<<<NN + 768 + init_blocks, 256, 0, stream>>>(
        s, gamma, beta, xh, Wqkv, WT, cur,
        (unsigned int*)col, (unsigned int*)qv);
    scatter_kernel<<<(NE + 255) / 256, 256, 0, stream>>>(src, dst, cur, col);
    gemm_kernel<<<1440, 256, 0, stream>>>(xh, WT, qv, ks);
    edge_kernel<<<dim3(8, (NN + 31) / 32), 256, 0, stream>>>(qv, ks, cur, col, out);
}